// Round 6
// baseline (16952.530 us; speedup 1.0000x reference)
//
#include <hip/hip_runtime.h>
#include <stdint.h>

#define H_ 1024
#define NG_ 4096   // 4*H

typedef float f32x4 __attribute__((ext_vector_type(4)));
typedef __bf16 bf16x8 __attribute__((ext_vector_type(8)));
typedef unsigned short us4 __attribute__((ext_vector_type(4)));

__device__ __forceinline__ unsigned short f2bf(float f) {
  union { float f; uint32_t u; } v; v.f = f;
  uint32_t r = v.u + 0x7FFFu + ((v.u >> 16) & 1u);
  return (unsigned short)(r >> 16);
}
__device__ __forceinline__ float bf2f(unsigned short b) {
  union { uint32_t u; float f; } v; v.u = ((uint32_t)b) << 16; return v.f;
}

__device__ __forceinline__ void gload_lds16(const void* g, void* l) {
  __builtin_amdgcn_global_load_lds(
      (const __attribute__((address_space(1))) void*)g,
      (__attribute__((address_space(3))) void*)l, 16, 0, 0);
}

__device__ __forceinline__ float sigm(float x) { return 1.f / (1.f + __expf(-x)); }
__device__ __forceinline__ float tanh_(float x) { return 1.f - 2.f / (__expf(2.f * x) + 1.f); }

// ---------------------------------------------------------------------------
// Weight prep: permute rows r = (j>>4)*64 + gate*16 + (j&15)  (old = gate*H + j)
// so a 64-wide column group holds 16 units x 4 gates, gate index = n-frag index.
// nt stores: weights are read by all XCDs -> push toward L3, keep writer L2 clean.
// ---------------------------------------------------------------------------
__global__ void prep_w0(const float* __restrict__ Whh0, unsigned short* __restrict__ Wr) {
  int i = (blockIdx.x * 256 + threadIdx.x) * 4;           // over 4096*1024
  int r = i >> 10, k = i & 1023;
  int gate = (r >> 4) & 3;
  int j = ((r >> 6) << 4) + (r & 15);
  const float4 v = *(const float4*)(Whh0 + (size_t)(gate * H_ + j) * H_ + k);
  us4 o; o.x = f2bf(v.x); o.y = f2bf(v.y); o.z = f2bf(v.z); o.w = f2bf(v.w);
  __builtin_nontemporal_store(o, (us4*)(Wr + i));
}

__global__ void prep_wcat(const float* __restrict__ Wih1, const float* __restrict__ Whh1,
                          unsigned short* __restrict__ Wr) {
  int i = (blockIdx.x * 256 + threadIdx.x) * 4;           // over 4096*2048
  int r = i >> 11, k = i & 2047;
  int gate = (r >> 4) & 3;
  int j = ((r >> 6) << 4) + (r & 15);
  const float* src = (k < 1024) ? (Wih1 + (size_t)(gate * H_ + j) * H_ + k)
                                : (Whh1 + (size_t)(gate * H_ + j) * H_ + (k - 1024));
  const float4 v = *(const float4*)src;
  us4 o; o.x = f2bf(v.x); o.y = f2bf(v.y); o.z = f2bf(v.z); o.w = f2bf(v.w);
  __builtin_nontemporal_store(o, (us4*)(Wr + (size_t)r * 2048 + k));
}

__global__ void prep_small(const float* __restrict__ Wih0,
                           const float* __restrict__ bih0, const float* __restrict__ bhh0,
                           const float* __restrict__ bih1, const float* __restrict__ bhh1,
                           float* __restrict__ bias0r, float* __restrict__ bias1r,
                           float* __restrict__ wi0r) {
  int r = blockIdx.x * 256 + threadIdx.x;                 // over 4096
  int gate = (r >> 4) & 3;
  int j = ((r >> 6) << 4) + (r & 15);
  int old = gate * H_ + j;
  bias0r[r] = bih0[old] + bhh0[old];
  bias1r[r] = bih1[old] + bhh1[old];
  wi0r[r * 2 + 0] = Wih0[old * 2 + 0];
  wi0r[r * 2 + 1] = Wih0[old * 2 + 1];
}

__global__ void prep_state(const float* __restrict__ h, const float* __restrict__ c,
                           unsigned short* __restrict__ h0b, unsigned short* __restrict__ h1b,
                           float* __restrict__ c0, float* __restrict__ c1, int bh) {
  int i = (blockIdx.x * 256 + threadIdx.x) * 4;           // over B*H
  float4 a = *(const float4*)(h + i);
  float4 b = *(const float4*)(h + (size_t)bh + i);
  us4 oa; oa.x = f2bf(a.x); oa.y = f2bf(a.y); oa.z = f2bf(a.z); oa.w = f2bf(a.w);
  us4 ob; ob.x = f2bf(b.x); ob.y = f2bf(b.y); ob.z = f2bf(b.z); ob.w = f2bf(b.w);
  __builtin_nontemporal_store(oa, (us4*)(h0b + i));
  __builtin_nontemporal_store(ob, (us4*)(h1b + i));
  *(float4*)(c0 + i) = *(const float4*)(c + i);
  *(float4*)(c1 + i) = *(const float4*)(c + (size_t)bh + i);
}

// ---------------------------------------------------------------------------
// Fused GEMM + LSTM cell. Tile 256(M) x 128(N), BK=64, 8 waves (4M x 2N),
// per-wave 64x64 output. A staged in LDS (dbuf 64 KB, XOR-swizzled,
// global_load_lds); B (weights) read DIRECTLY global->reg (L2-resident
// panels). 2 blocks/CU co-resident (16 waves/CU) hide fetch latency.
// Per K-tile: [B ks0 loads][stage A(u+1)][ds+MFMA ks0][B ks1][ds+MFMA ks1]
//             [vmcnt(0) ~free][s_barrier]. Compiler inserts counted B-waits
//             that leave the A-prefetch in flight (issue order!).
// ---------------------------------------------------------------------------
__global__ void __launch_bounds__(512, 4)
lstm_gemm_cell(const unsigned short* __restrict__ A0,
               const unsigned short* __restrict__ A1,
               int Ktot,
               const unsigned short* __restrict__ Bw,
               const float* __restrict__ biasr,
               const float* __restrict__ wi0r,
               const int* __restrict__ xidx,
               int have_x,
               float* __restrict__ Cst,
               unsigned short* __restrict__ Hout) {
  __shared__ unsigned short As[2][256 * 64];   // 64 KB total

  const int tid  = threadIdx.x;
  const int lane = tid & 63;
  const int wv   = tid >> 6;          // 0..7
  const int wm   = wv >> 1;           // 0..3  (M quarter, 64 rows)
  const int wn   = wv & 1;            // 0..1  (N half, 64 cols)
  const int tile_m = blockIdx.y * 256;
  const int tile_n = blockIdx.x * 128;

  // staging geometry: one gload round = 512 thr x 16B = 64 rows of [64 bf16]
  const int rowt = tid >> 3;                          // 0..63
  const int cb8  = (tid & 7) * 8;                     // LDS col, linear dest
  const int ce   = (((tid & 7) ^ (rowt & 7)) * 8);    // global col: inv-swizzled src

  const int NK = Ktot >> 6;

  auto stageA = [&](int v) {                          // full 32 KB A K-slab
    const int d = v & 1;
    const int kb = v << 6;
    const unsigned short* Ap = A0; int kl = kb;
    if (kb >= 1024) { Ap = A1; kl = kb - 1024; }
#pragma unroll
    for (int i = 0; i < 4; ++i) {
      const int row = i * 64 + rowt;
      gload_lds16(Ap + (size_t)(tile_m + row) * H_ + kl + ce, (void*)&As[d][row * 64 + cb8]);
    }
  };

  f32x4 acc[4][4];
#pragma unroll
  for (int m = 0; m < 4; ++m)
#pragma unroll
    for (int n = 0; n < 4; ++n) acc[m][n] = (f32x4)0.f;

  const int cl  = lane & 15;
  const int khi = lane >> 4;          // 0..3
  const int ksw0 = ((0 + khi) ^ (cl & 7)) * 16;   // swizzled byte off, ks=0
  const int ksw1 = ((4 + khi) ^ (cl & 7)) * 16;   // ks=1

  // B direct-from-global addressing: frag(n,ks) lane -> row tile_n+wn*64+n*16+cl
  const size_t Kb2 = (size_t)Ktot * 2;            // row stride bytes
  const char* Bbase = (const char*)Bw + (size_t)(tile_n + wn * 64 + cl) * Kb2 + khi * 16;
  const size_t Bn = 16 * Kb2;                      // n-frag stride (16 rows)

  // ---- prologue ----
  stageA(0);
  asm volatile("s_waitcnt vmcnt(0)" ::: "memory");
  __builtin_amdgcn_sched_barrier(0);
  __builtin_amdgcn_s_barrier();

  for (int u = 0; u < NK; ++u) {
    const char* Ab = (const char*)&As[u & 1][0] + (wm * 64 + cl) * 128;
    const char* Bu = Bbase + (size_t)u * 128;

    // B ks0 frags (oldest VMEM this tile), then A prefetch (stays in flight)
    bf16x8 bX[4];
#pragma unroll
    for (int n = 0; n < 4; ++n) bX[n] = *(const bf16x8*)(Bu + (size_t)n * Bn);
    if (u + 1 < NK) stageA(u + 1);
    __builtin_amdgcn_sched_barrier(0);

    // ks0
    bf16x8 aX[4];
#pragma unroll
    for (int m = 0; m < 4; ++m) aX[m] = *(const bf16x8*)(Ab + m * 2048 + ksw0);
    __builtin_amdgcn_s_setprio(1);
#pragma unroll
    for (int m = 0; m < 4; ++m)
#pragma unroll
      for (int n = 0; n < 4; ++n)
        acc[m][n] = __builtin_amdgcn_mfma_f32_16x16x32_bf16(aX[m], bX[n], acc[m][n], 0, 0, 0);
    __builtin_amdgcn_s_setprio(0);

    // ks1
    bf16x8 bY[4];
#pragma unroll
    for (int n = 0; n < 4; ++n) bY[n] = *(const bf16x8*)(Bu + (size_t)n * Bn + 64);
    bf16x8 aY[4];
#pragma unroll
    for (int m = 0; m < 4; ++m) aY[m] = *(const bf16x8*)(Ab + m * 2048 + ksw1);
    __builtin_amdgcn_s_setprio(1);
#pragma unroll
    for (int m = 0; m < 4; ++m)
#pragma unroll
      for (int n = 0; n < 4; ++n)
        acc[m][n] = __builtin_amdgcn_mfma_f32_16x16x32_bf16(aY[m], bY[n], acc[m][n], 0, 0, 0);
    __builtin_amdgcn_s_setprio(0);

    // A(u+1) was issued a full tile ago -> this drain is ~free
    asm volatile("s_waitcnt vmcnt(0)" ::: "memory");
    __builtin_amdgcn_sched_barrier(0);
    __builtin_amdgcn_s_barrier();
  }

  // ---- epilogue: fused LSTM cell (gate = n-frag index) ----
  const int jgrp = (tile_n >> 6) + wn;
  const int j = jgrp * 16 + cl;
  float bias[4], w0v[4] = {0, 0, 0, 0}, w1v[4] = {0, 0, 0, 0};
#pragma unroll
  for (int n = 0; n < 4; ++n) {
    int colr = tile_n + wn * 64 + n * 16 + cl;
    bias[n] = biasr[colr];
    if (have_x) { w0v[n] = wi0r[colr * 2]; w1v[n] = wi0r[colr * 2 + 1]; }
  }
#pragma unroll
  for (int m = 0; m < 4; ++m) {
#pragma unroll
    for (int q = 0; q < 4; ++q) {
      int row = tile_m + wm * 64 + m * 16 + khi * 4 + q;
      float gi = acc[m][0][q] + bias[0];
      float gf = acc[m][1][q] + bias[1];
      float gg = acc[m][2][q] + bias[2];
      float go = acc[m][3][q] + bias[3];
      if (have_x) {
        int x = xidx[row];
        gi += x ? w1v[0] : w0v[0];
        gf += x ? w1v[1] : w0v[1];
        gg += x ? w1v[2] : w0v[2];
        go += x ? w1v[3] : w0v[3];
      }
      size_t off = (size_t)row * H_ + j;
      float cp = Cst[off];
      float cn = sigm(gf) * cp + sigm(gi) * tanh_(gg);
      float hn = sigm(go) * tanh_(cn);
      Cst[off] = cn;
      __builtin_nontemporal_store(f2bf(hn), Hout + off);  // next kernel reads cross-XCD
    }
  }
}

// ---------------------------------------------------------------------------
// fc head: logits = h1 @ fcW^T + fcb, write out[b,t,:], argmax -> xidx
// ---------------------------------------------------------------------------
__global__ void fc_argmax(const unsigned short* __restrict__ h1,
                          const float* __restrict__ fcW, const float* __restrict__ fcb,
                          float* __restrict__ out, int* __restrict__ xidx,
                          int t, int pred_len) {
  const int lane = threadIdx.x & 63;
  const int wv = threadIdx.x >> 6;
  const int row = blockIdx.x * 4 + wv;
  const unsigned short* hp = h1 + (size_t)row * H_ + lane * 16;
  float d0 = 0.f, d1 = 0.f;
#pragma unroll
  for (int u = 0; u < 2; ++u) {
    ushort4 ha = *(const ushort4*)(hp + u * 8);
    ushort4 hb = *(const ushort4*)(hp + u * 8 + 4);
    float hv[8] = { bf2f(ha.x), bf2f(ha.y), bf2f(ha.z), bf2f(ha.w),
                    bf2f(hb.x), bf2f(hb.y), bf2f(hb.z), bf2f(hb.w) };
#pragma unroll
    for (int e = 0; e < 8; ++e) {
      int k = lane * 16 + u * 8 + e;
      d0 += hv[e] * fcW[k];
      d1 += hv[e] * fcW[H_ + k];
    }
  }
#pragma unroll
  for (int off = 32; off > 0; off >>= 1) {
    d0 += __shfl_xor(d0, off);
    d1 += __shfl_xor(d1, off);
  }
  if (lane == 0) {
    d0 += fcb[0]; d1 += fcb[1];
    size_t o = ((size_t)row * pred_len + t) * 2;
    out[o] = d0; out[o + 1] = d1;
    xidx[row] = (d1 > d0) ? 1 : 0;
  }
}

// ---------------------------------------------------------------------------
extern "C" void kernel_launch(void* const* d_in, const int* in_sizes, int n_in,
                              void* d_out, int out_size, void* d_ws, size_t ws_size,
                              hipStream_t stream) {
  const float* h     = (const float*)d_in[0];
  const float* c     = (const float*)d_in[1];
  const float* Wih0  = (const float*)d_in[2];
  const float* Whh0  = (const float*)d_in[3];
  const float* bih0  = (const float*)d_in[4];
  const float* bhh0  = (const float*)d_in[5];
  const float* Wih1  = (const float*)d_in[6];
  const float* Whh1  = (const float*)d_in[7];
  const float* bih1  = (const float*)d_in[8];
  const float* bhh1  = (const float*)d_in[9];
  const float* fcW   = (const float*)d_in[10];
  const float* fcb   = (const float*)d_in[11];

  const int B = in_sizes[0] / (2 * H_);           // 4096
  const int pred_len = out_size / (B * 2);        // 64
  const int BH = B * H_;                          // 4194304

  size_t off = 0;
  auto carve = [&](size_t bytes) -> void* {
    void* p = (char*)d_ws + off;
    off += (bytes + 255) & ~(size_t)255;
    return p;
  };
  unsigned short* Whh0r = (unsigned short*)carve((size_t)NG_ * 1024 * 2);
  unsigned short* Wcatr = (unsigned short*)carve((size_t)NG_ * 2048 * 2);
  unsigned short* h0b[2], *h1b[2];
  h0b[0] = (unsigned short*)carve((size_t)BH * 2);
  h0b[1] = (unsigned short*)carve((size_t)BH * 2);
  h1b[0] = (unsigned short*)carve((size_t)BH * 2);
  h1b[1] = (unsigned short*)carve((size_t)BH * 2);
  float* c0 = (float*)carve((size_t)BH * 4);
  float* c1 = (float*)carve((size_t)BH * 4);
  float* bias0r = (float*)carve(NG_ * 4);
  float* bias1r = (float*)carve(NG_ * 4);
  float* wi0r   = (float*)carve(NG_ * 2 * 4);
  int*   xidx   = (int*)carve(B * 4);

  hipLaunchKernelGGL(prep_w0,   dim3((NG_ * 1024 / 4) / 256), dim3(256), 0, stream, Whh0, Whh0r);
  hipLaunchKernelGGL(prep_wcat, dim3((NG_ * 2048 / 4) / 256), dim3(256), 0, stream, Wih1, Whh1, Wcatr);
  hipLaunchKernelGGL(prep_small, dim3(NG_ / 256), dim3(256), 0, stream,
                     Wih0, bih0, bhh0, bih1, bhh1, bias0r, bias1r, wi0r);
  hipLaunchKernelGGL(prep_state, dim3((BH / 4) / 256), dim3(256), 0, stream,
                     h, c, h0b[0], h1b[0], c0, c1, BH);

  dim3 ggrid(NG_ / 128, B / 256);                 // 32 x 16 = 512 blocks (2/CU)
  dim3 gblk(512);
  float* out = (float*)d_out;

  for (int t = 0; t < pred_len; ++t) {
    const int cur = t & 1, nxt = cur ^ 1;
    hipLaunchKernelGGL(lstm_gemm_cell, ggrid, gblk, 0, stream,
                       h0b[cur], (const unsigned short*)nullptr, 1024, Whh0r,
                       bias0r, wi0r, xidx, (t > 0) ? 1 : 0, c0, h0b[nxt]);
    hipLaunchKernelGGL(lstm_gemm_cell, ggrid, gblk, 0, stream,
                       h0b[nxt], h1b[cur], 2048, Wcatr,
                       bias1r, (const float*)nullptr, (const int*)nullptr, 0, c1, h1b[nxt]);
    hipLaunchKernelGGL(fc_argmax, dim3(B / 4), dim3(256), 0, stream,
                       h1b[nxt], fcW, fcb, out, xidx, t, pred_len);
  }
}

// Round 7
// 7340.274 us; speedup vs baseline: 2.3095x; 2.3095x over previous
//
#include <hip/hip_runtime.h>
#include <stdint.h>

#define H_ 1024
#define NG_ 4096   // 4*H

typedef float f32x4 __attribute__((ext_vector_type(4)));
typedef __bf16 bf16x8 __attribute__((ext_vector_type(8)));

__device__ __forceinline__ unsigned short f2bf(float f) {
  union { float f; uint32_t u; } v; v.f = f;
  uint32_t r = v.u + 0x7FFFu + ((v.u >> 16) & 1u);
  return (unsigned short)(r >> 16);
}
__device__ __forceinline__ float bf2f(unsigned short b) {
  union { uint32_t u; float f; } v; v.u = ((uint32_t)b) << 16; return v.f;
}

__device__ __forceinline__ void gload_lds16(const void* g, void* l) {
  __builtin_amdgcn_global_load_lds(
      (const __attribute__((address_space(1))) void*)g,
      (__attribute__((address_space(3))) void*)l, 16, 0, 0);
}

__device__ __forceinline__ float sigm(float x) { return 1.f / (1.f + __expf(-x)); }
__device__ __forceinline__ float tanh_(float x) { return 1.f - 2.f / (__expf(2.f * x) + 1.f); }

// ---------------------------------------------------------------------------
// Weight prep: permute rows r = (j>>4)*64 + gate*16 + (j&15)  (old = gate*H + j)
// so a 64-wide column group holds 16 units x 4 gates, gate index = n-frag index.
// ---------------------------------------------------------------------------
__global__ void prep_w0(const float* __restrict__ Whh0, unsigned short* __restrict__ Wr) {
  int i = (blockIdx.x * 256 + threadIdx.x) * 4;           // over 4096*1024
  int r = i >> 10, k = i & 1023;
  int gate = (r >> 4) & 3;
  int j = ((r >> 6) << 4) + (r & 15);
  const float4 v = *(const float4*)(Whh0 + (size_t)(gate * H_ + j) * H_ + k);
  ushort4 o; o.x = f2bf(v.x); o.y = f2bf(v.y); o.z = f2bf(v.z); o.w = f2bf(v.w);
  *(ushort4*)(Wr + i) = o;
}

__global__ void prep_wcat(const float* __restrict__ Wih1, const float* __restrict__ Whh1,
                          unsigned short* __restrict__ Wr) {
  int i = (blockIdx.x * 256 + threadIdx.x) * 4;           // over 4096*2048
  int r = i >> 11, k = i & 2047;
  int gate = (r >> 4) & 3;
  int j = ((r >> 6) << 4) + (r & 15);
  const float* src = (k < 1024) ? (Wih1 + (size_t)(gate * H_ + j) * H_ + k)
                                : (Whh1 + (size_t)(gate * H_ + j) * H_ + (k - 1024));
  const float4 v = *(const float4*)src;
  ushort4 o; o.x = f2bf(v.x); o.y = f2bf(v.y); o.z = f2bf(v.z); o.w = f2bf(v.w);
  *(ushort4*)(Wr + (size_t)r * 2048 + k) = o;
}

__global__ void prep_small(const float* __restrict__ Wih0,
                           const float* __restrict__ bih0, const float* __restrict__ bhh0,
                           const float* __restrict__ bih1, const float* __restrict__ bhh1,
                           float* __restrict__ bias0r, float* __restrict__ bias1r,
                           float* __restrict__ wi0r) {
  int r = blockIdx.x * 256 + threadIdx.x;                 // over 4096
  int gate = (r >> 4) & 3;
  int j = ((r >> 6) << 4) + (r & 15);
  int old = gate * H_ + j;
  bias0r[r] = bih0[old] + bhh0[old];
  bias1r[r] = bih1[old] + bhh1[old];
  wi0r[r * 2 + 0] = Wih0[old * 2 + 0];
  wi0r[r * 2 + 1] = Wih0[old * 2 + 1];
}

__global__ void prep_state(const float* __restrict__ h, const float* __restrict__ c,
                           unsigned short* __restrict__ h0b, unsigned short* __restrict__ h1b,
                           float* __restrict__ c0, float* __restrict__ c1, int bh) {
  int i = (blockIdx.x * 256 + threadIdx.x) * 4;           // over B*H
  float4 a = *(const float4*)(h + i);
  float4 b = *(const float4*)(h + (size_t)bh + i);
  ushort4 oa; oa.x = f2bf(a.x); oa.y = f2bf(a.y); oa.z = f2bf(a.z); oa.w = f2bf(a.w);
  ushort4 ob; ob.x = f2bf(b.x); ob.y = f2bf(b.y); ob.z = f2bf(b.z); ob.w = f2bf(b.w);
  *(ushort4*)(h0b + i) = oa;
  *(ushort4*)(h1b + i) = ob;
  *(float4*)(c0 + i) = *(const float4*)(c + i);
  *(float4*)(c1 + i) = *(const float4*)(c + (size_t)bh + i);
}

// ---------------------------------------------------------------------------
// Fused GEMM + LSTM cell.  EXACT R1 structure (128x128 tile, BK=64, 4 waves,
// single-buffered LDS, 3-4 blocks/CU occupancy-pipelined) + both-sides XOR
// swizzle to kill the 16-way ds_read bank conflict:
//   physical slot s_phys = s_log ^ (row & 7)   (slot = 16-byte chunk, 8/row)
//   - stage: linear LDS dest (gload_lds lane-order), global src col pre-XORed
//   - read : ds_read at slot (ks*4+khi) ^ (lane&7)
// ---------------------------------------------------------------------------
__global__ void lstm_gemm_cell(const unsigned short* __restrict__ A0,
                               const unsigned short* __restrict__ A1,
                               int Ktot,
                               const unsigned short* __restrict__ Bw,
                               const float* __restrict__ biasr,
                               const float* __restrict__ wi0r,
                               const int* __restrict__ xidx,
                               int have_x,
                               float* __restrict__ Cst,
                               unsigned short* __restrict__ Hout) {
  __shared__ unsigned short As[128 * 64];
  __shared__ unsigned short Bs[128 * 64];
  const int tid  = threadIdx.x;
  const int lane = tid & 63;
  const int wv   = tid >> 6;
  const int wm   = wv >> 1, wn = wv & 1;
  const int tile_m = blockIdx.y * 128;
  const int tile_n = blockIdx.x * 128;

  f32x4 acc[4][4];
#pragma unroll
  for (int m = 0; m < 4; ++m)
#pragma unroll
    for (int n = 0; n < 4; ++n) acc[m][n] = (f32x4)0.f;

  // staging: chunk = 8 rows x 64 cols; lane covers row lane>>3, slot lane&7.
  // dest is linear (base + lane*16); source col slot pre-XORed by row&7.
  const int lrow = lane >> 3;                      // row within chunk (= row&7)
  const int lk   = ((lane & 7) ^ lrow) * 8;        // inv-swizzled global col (elems)

  const int nk = Ktot >> 6;
  for (int kt = 0; kt < nk; ++kt) {
    const int k0 = kt << 6;
    const unsigned short* Ap; int kl;
    if (k0 < 1024) { Ap = A0; kl = k0; } else { Ap = A1; kl = k0 - 1024; }
#pragma unroll
    for (int i = 0; i < 4; ++i) {
      int chunk = wv * 4 + i;
      int row = chunk * 8 + lrow;
      gload_lds16(Ap + (size_t)(tile_m + row) * H_ + kl + lk, (void*)&As[chunk * 512]);
    }
#pragma unroll
    for (int i = 0; i < 4; ++i) {
      int chunk = wv * 4 + i;
      int row = chunk * 8 + lrow;
      gload_lds16(Bw + (size_t)(tile_n + row) * Ktot + k0 + lk, (void*)&Bs[chunk * 512]);
    }
    __syncthreads();

    const char* Ab = (const char*)As;
    const char* Bb = (const char*)Bs;
    const int arow = wm * 64 + (lane & 15);
    const int brow = wn * 64 + (lane & 15);
    const int khi  = lane >> 4;                    // 0..3
    const int x7   = lane & 7;                     // row&7 of the rows this lane reads
    const int ksw0 = ((0 + khi) ^ x7) * 16;        // physical byte off, ks=0
    const int ksw1 = ((4 + khi) ^ x7) * 16;        // ks=1
#pragma unroll
    for (int ks = 0; ks < 2; ++ks) {
      const int ksw = ks ? ksw1 : ksw0;
      bf16x8 af[4], bfr[4];
#pragma unroll
      for (int m = 0; m < 4; ++m)
        af[m] = *(const bf16x8*)(Ab + (arow + m * 16) * 128 + ksw);
#pragma unroll
      for (int n = 0; n < 4; ++n)
        bfr[n] = *(const bf16x8*)(Bb + (brow + n * 16) * 128 + ksw);
#pragma unroll
      for (int m = 0; m < 4; ++m)
#pragma unroll
        for (int n = 0; n < 4; ++n)
          acc[m][n] = __builtin_amdgcn_mfma_f32_16x16x32_bf16(af[m], bfr[n], acc[m][n], 0, 0, 0);
    }
    __syncthreads();
  }

  // ---- epilogue: fused LSTM cell ----
  const int cl = lane & 15;
  const int rq = (lane >> 4) * 4;
  const int jgrp = (tile_n >> 6) + wn;             // (tile_n + wn*64)/64
  const int j = jgrp * 16 + cl;
  float bias[4], w0v[4] = {0, 0, 0, 0}, w1v[4] = {0, 0, 0, 0};
#pragma unroll
  for (int n = 0; n < 4; ++n) {
    int colr = tile_n + wn * 64 + n * 16 + cl;
    bias[n] = biasr[colr];
    if (have_x) { w0v[n] = wi0r[colr * 2]; w1v[n] = wi0r[colr * 2 + 1]; }
  }
#pragma unroll
  for (int m = 0; m < 4; ++m) {
#pragma unroll
    for (int q = 0; q < 4; ++q) {
      int row = tile_m + wm * 64 + m * 16 + rq + q;
      float gi = acc[m][0][q] + bias[0];
      float gf = acc[m][1][q] + bias[1];
      float gg = acc[m][2][q] + bias[2];
      float go = acc[m][3][q] + bias[3];
      if (have_x) {
        int x = xidx[row];
        gi += x ? w1v[0] : w0v[0];
        gf += x ? w1v[1] : w0v[1];
        gg += x ? w1v[2] : w0v[2];
        go += x ? w1v[3] : w0v[3];
      }
      size_t off = (size_t)row * H_ + j;
      float cp = Cst[off];
      float cn = sigm(gf) * cp + sigm(gi) * tanh_(gg);
      float hn = sigm(go) * tanh_(cn);
      Cst[off] = cn;
      Hout[off] = f2bf(hn);
    }
  }
}

// ---------------------------------------------------------------------------
// fc head: logits = h1 @ fcW^T + fcb, write out[b,t,:], argmax -> xidx
// ---------------------------------------------------------------------------
__global__ void fc_argmax(const unsigned short* __restrict__ h1,
                          const float* __restrict__ fcW, const float* __restrict__ fcb,
                          float* __restrict__ out, int* __restrict__ xidx,
                          int t, int pred_len) {
  const int lane = threadIdx.x & 63;
  const int wv = threadIdx.x >> 6;
  const int row = blockIdx.x * 4 + wv;
  const unsigned short* hp = h1 + (size_t)row * H_ + lane * 16;
  float d0 = 0.f, d1 = 0.f;
#pragma unroll
  for (int u = 0; u < 2; ++u) {
    ushort4 ha = *(const ushort4*)(hp + u * 8);
    ushort4 hb = *(const ushort4*)(hp + u * 8 + 4);
    float hv[8] = { bf2f(ha.x), bf2f(ha.y), bf2f(ha.z), bf2f(ha.w),
                    bf2f(hb.x), bf2f(hb.y), bf2f(hb.z), bf2f(hb.w) };
#pragma unroll
    for (int e = 0; e < 8; ++e) {
      int k = lane * 16 + u * 8 + e;
      d0 += hv[e] * fcW[k];
      d1 += hv[e] * fcW[H_ + k];
    }
  }
#pragma unroll
  for (int off = 32; off > 0; off >>= 1) {
    d0 += __shfl_xor(d0, off);
    d1 += __shfl_xor(d1, off);
  }
  if (lane == 0) {
    d0 += fcb[0]; d1 += fcb[1];
    size_t o = ((size_t)row * pred_len + t) * 2;
    out[o] = d0; out[o + 1] = d1;
    xidx[row] = (d1 > d0) ? 1 : 0;
  }
}

// ---------------------------------------------------------------------------
extern "C" void kernel_launch(void* const* d_in, const int* in_sizes, int n_in,
                              void* d_out, int out_size, void* d_ws, size_t ws_size,
                              hipStream_t stream) {
  const float* h     = (const float*)d_in[0];
  const float* c     = (const float*)d_in[1];
  const float* Wih0  = (const float*)d_in[2];
  const float* Whh0  = (const float*)d_in[3];
  const float* bih0  = (const float*)d_in[4];
  const float* bhh0  = (const float*)d_in[5];
  const float* Wih1  = (const float*)d_in[6];
  const float* Whh1  = (const float*)d_in[7];
  const float* bih1  = (const float*)d_in[8];
  const float* bhh1  = (const float*)d_in[9];
  const float* fcW   = (const float*)d_in[10];
  const float* fcb   = (const float*)d_in[11];

  const int B = in_sizes[0] / (2 * H_);           // 4096
  const int pred_len = out_size / (B * 2);        // 64
  const int BH = B * H_;                          // 4194304

  size_t off = 0;
  auto carve = [&](size_t bytes) -> void* {
    void* p = (char*)d_ws + off;
    off += (bytes + 255) & ~(size_t)255;
    return p;
  };
  unsigned short* Whh0r = (unsigned short*)carve((size_t)NG_ * 1024 * 2);
  unsigned short* Wcatr = (unsigned short*)carve((size_t)NG_ * 2048 * 2);
  unsigned short* h0b[2], *h1b[2];
  h0b[0] = (unsigned short*)carve((size_t)BH * 2);
  h0b[1] = (unsigned short*)carve((size_t)BH * 2);
  h1b[0] = (unsigned short*)carve((size_t)BH * 2);
  h1b[1] = (unsigned short*)carve((size_t)BH * 2);
  float* c0 = (float*)carve((size_t)BH * 4);
  float* c1 = (float*)carve((size_t)BH * 4);
  float* bias0r = (float*)carve(NG_ * 4);
  float* bias1r = (float*)carve(NG_ * 4);
  float* wi0r   = (float*)carve(NG_ * 2 * 4);
  int*   xidx   = (int*)carve(B * 4);

  hipLaunchKernelGGL(prep_w0,   dim3((NG_ * 1024 / 4) / 256), dim3(256), 0, stream, Whh0, Whh0r);
  hipLaunchKernelGGL(prep_wcat, dim3((NG_ * 2048 / 4) / 256), dim3(256), 0, stream, Wih1, Whh1, Wcatr);
  hipLaunchKernelGGL(prep_small, dim3(NG_ / 256), dim3(256), 0, stream,
                     Wih0, bih0, bhh0, bih1, bhh1, bias0r, bias1r, wi0r);
  hipLaunchKernelGGL(prep_state, dim3((BH / 4) / 256), dim3(256), 0, stream,
                     h, c, h0b[0], h1b[0], c0, c1, BH);

  dim3 ggrid(NG_ / 128, B / 128);                 // 32 x 32 = 1024 blocks
  dim3 gblk(256);
  float* out = (float*)d_out;

  for (int t = 0; t < pred_len; ++t) {
    const int cur = t & 1, nxt = cur ^ 1;
    hipLaunchKernelGGL(lstm_gemm_cell, ggrid, gblk, 0, stream,
                       h0b[cur], (const unsigned short*)nullptr, 1024, Whh0r,
                       bias0r, wi0r, xidx, (t > 0) ? 1 : 0, c0, h0b[nxt]);
    hipLaunchKernelGGL(lstm_gemm_cell, ggrid, gblk, 0, stream,
                       h0b[nxt], h1b[cur], 2048, Wcatr,
                       bias1r, (const float*)nullptr, (const int*)nullptr, 0, c1, h1b[nxt]);
    hipLaunchKernelGGL(fc_argmax, dim3(B / 4), dim3(256), 0, stream,
                       h1b[nxt], fcW, fcb, out, xidx, t, pred_len);
  }
}